// Round 3
// baseline (488.509 us; speedup 1.0000x reference)
//
#include <hip/hip_runtime.h>

// Problem: B=32, S=4096, H=768, fp32.
// start_logits[b,s] = sum_h hidden[b,s,h] * w_start[h]
// end_logits[b,s]   = sum_h hidden[b,s,h] * w_end[h]
// Output: concat(start, end) flat -> 2*B*S floats.
//
// Memory-bound streaming reduce: 402.7 MB read, 1 MB write; HBM floor ~63 us.
//
// R3 structure: wave64 = 4 quarters x 16 lanes. Each quarter owns one row of
// a 4-row group; one width-16 butterfly (4 steps) reduces 4 rows at once.
// ds-pipe ops per wave: 4 groups x 8 + 2 final = 34 (was 194 in R2).
// VMEM count unchanged: 3 x float4 per row, nontemporal (no reuse, spare L2).
// Weights held in registers (24 x f32x4); final shfl gather -> coalesced store.

#define ROWS (32 * 4096)       // 131072
#define HDIM 768

typedef float f32x4 __attribute__((ext_vector_type(4)));

__global__ __launch_bounds__(256) void qa_logits_kernel(
    const float* __restrict__ hs,
    const float* __restrict__ w_start,
    const float* __restrict__ w_end,
    float* __restrict__ out) {

    const int lane = threadIdx.x & 63;
    const int wave = (blockIdx.x * blockDim.x + threadIdx.x) >> 6;
    const int row0 = wave * 16;
    const int i = lane & 15;   // lane within quarter
    const int q = lane >> 4;   // quarter 0..3

    // Weight fragments: lane-in-quarter i covers elems j*64 + 4i .. +3.
    f32x4 wa[12], wb[12];
#pragma unroll
    for (int j = 0; j < 12; ++j) {
        wa[j] = *(const f32x4*)(w_start + j * 64 + i * 4);
        wb[j] = *(const f32x4*)(w_end   + j * 64 + i * 4);
    }

    float s_keep = 0.f, e_keep = 0.f;

#pragma unroll
    for (int g = 0; g < 4; ++g) {
        const int row = row0 + g * 4 + q;           // quarter q owns this row
        const float* __restrict__ rp = hs + (size_t)row * HDIM + i * 4;
        float s = 0.f, e = 0.f;
#pragma unroll
        for (int j = 0; j < 12; ++j) {
            const f32x4 h = __builtin_nontemporal_load((const f32x4*)(rp + j * 64));
            s += h.x * wa[j].x + h.y * wa[j].y + h.z * wa[j].z + h.w * wa[j].w;
            e += h.x * wb[j].x + h.y * wb[j].y + h.z * wb[j].z + h.w * wb[j].w;
        }
        // One 4-step butterfly reduces all 4 rows of the group at once.
#pragma unroll
        for (int off = 8; off > 0; off >>= 1) {
            s += __shfl_xor(s, off, 16);
            e += __shfl_xor(e, off, 16);
        }
        // Row r0+4g+q parked on lane 16q+g.
        if ((lane & 15) == g) { s_keep = s; e_keep = e; }
    }

    // Gather: lane l<16 wants row r0+l (l = 4g+q) -> source lane 16*(l&3)+(l>>2).
    const int src = 16 * (lane & 3) + ((lane >> 2) & 3);
    const float s_o = __shfl(s_keep, src, 64);
    const float e_o = __shfl(e_keep, src, 64);
    if (lane < 16) {
        out[row0 + lane] = s_o;          // start_logits, 64 B coalesced
        out[ROWS + row0 + lane] = e_o;   // end_logits,   64 B coalesced
    }
}

extern "C" void kernel_launch(void* const* d_in, const int* in_sizes, int n_in,
                              void* d_out, int out_size, void* d_ws, size_t ws_size,
                              hipStream_t stream) {
    const float* hs      = (const float*)d_in[0];
    const float* w_start = (const float*)d_in[1];
    const float* w_end   = (const float*)d_in[2];
    float* out = (float*)d_out;

    // 131072 rows / 16 rows-per-wave = 8192 waves = 2048 blocks x 4 waves.
    const int blocks = ROWS / (16 * 4);
    qa_logits_kernel<<<blocks, 256, 0, stream>>>(hs, w_start, w_end, out);
}